// Round 3
// baseline (355.709 us; speedup 1.0000x reference)
//
#include <hip/hip_runtime.h>
#include <hip/hip_bf16.h>

#define BB 32
#define NN 128
#define SD 128
#define ED 32
#define ID 256
#define BN (BB*NN)   // 4096
#define NI 4         // i-blocks per k2 workgroup

typedef __attribute__((ext_vector_type(8))) short sh8;
typedef __attribute__((ext_vector_type(4))) float f32x4;

__device__ __forceinline__ float ftanh(float x) {
    float e2 = __expf(2.0f * x);
    return 1.0f - 2.0f * __builtin_amdgcn_rcpf(e2 + 1.0f);
}

__device__ __forceinline__ ushort f2bf(float f) {
    unsigned u = __float_as_uint(f);
    return (ushort)((u + 0x7FFF + ((u >> 16) & 1)) >> 16);
}

// ---------------------------------------------------------------------------
// prep: B-fragments of We = W1[256:288, :] (K=32), bf16, frag-ordered.
// tile = mat*16 + nt (nt over 16 col-tiles). lane l holds We[k=(l>>4)*8+e][col=nt*16+(l&15)]
// grid 32, block 64
// ---------------------------------------------------------------------------
__global__ void k_prep_w(const float* __restrict__ Wg1, const float* __restrict__ Wm1,
                         ushort* __restrict__ Bprep) {
    const int tile = blockIdx.x;
    const int l = threadIdx.x;
    const int mat = tile >> 4;
    const int nt = tile & 15;
    const float* W = mat ? Wm1 : Wg1;
    const int col = nt * 16 + (l & 15);
    const int kbase = (l >> 4) * 8;
    sh8 v;
    #pragma unroll
    for (int e = 0; e < 8; ++e)
        v[e] = (short)f2bf(W[(size_t)(2 * SD + kbase + e) * ID + col]);
    *(sh8*)&Bprep[(size_t)tile * 512 + l * 8] = v;
}

// ---------------------------------------------------------------------------
// K1: node projections (f32, exact):
// which 0: Hgi = h@Wg1[0:128]+bg1   1: Hgj = h@Wg1[128:256]
//       2: Hmi = h@Wm1[0:128]+bm1   3: Hmj = h@Wm1[128:256]
// grid (BN/32, 4), block 256
// ---------------------------------------------------------------------------
__global__ void k1_preproj(const float* __restrict__ h,
                           const float* __restrict__ Wg1, const float* __restrict__ bg1,
                           const float* __restrict__ Wm1, const float* __restrict__ bm1,
                           float* __restrict__ Hgi, float* __restrict__ Hgj,
                           float* __restrict__ Hmi, float* __restrict__ Hmj) {
    const int tile = blockIdx.x;
    const int which = blockIdx.y;
    __shared__ float hs[32][SD];
    const int t = threadIdx.x;
    const float* hrow = h + (size_t)tile * 32 * SD;
    for (int i = t; i < 32 * SD; i += 256) hs[i >> 7][i & 127] = hrow[i];
    __syncthreads();
    const float* W; const float* bias = nullptr; float* out;
    if (which == 0)      { W = Wg1;           bias = bg1; out = Hgi; }
    else if (which == 1) { W = Wg1 + SD * ID;             out = Hgj; }
    else if (which == 2) { W = Wm1;           bias = bm1; out = Hmi; }
    else                 { W = Wm1 + SD * ID;             out = Hmj; }
    const int k = t;
    float acc[32];
    const float b0 = bias ? bias[k] : 0.0f;
    #pragma unroll
    for (int r = 0; r < 32; ++r) acc[r] = b0;
    #pragma unroll 4
    for (int c = 0; c < SD; ++c) {
        const float wv = W[c * ID + k];
        #pragma unroll
        for (int r = 0; r < 32; ++r) acc[r] = fmaf(hs[r][c], wv, acc[r]);
    }
    #pragma unroll
    for (int r = 0; r < 32; ++r) out[(size_t)(tile * 32 + r) * ID + k] = acc[r];
}

// ---------------------------------------------------------------------------
// K2: NI consecutive i's of one b per block. E-proj via MFMA (K=32, bf16),
// + f32 Hgi[k] + Hgj[j,k] (global, L2-hit, amortized over NI).
// E staged linearly (conflict-free writes + conflict-free frag reads).
// grid BN/NI, block 256
// ---------------------------------------------------------------------------
__global__ __launch_bounds__(256, 3) void k2_edges(
        const float* __restrict__ ef, const float* __restrict__ em,
        const ushort* __restrict__ Bprep,
        const float* __restrict__ Hgi, const float* __restrict__ Hmi,
        const float* __restrict__ Hgj, const float* __restrict__ Hmj,
        const float* __restrict__ Wg2, const float* __restrict__ bg2,
        float* __restrict__ T, float* __restrict__ gsum, float* __restrict__ deg) {
    const int bi0 = blockIdx.x * NI;
    const int b = bi0 >> 7;
    const int t = threadIdx.x;
    const int w = t >> 6;
    const int lane = t & 63;
    const int col = lane & 15;
    const int grp = lane >> 4;

    __shared__ __align__(16) ushort Elds[NI * 8 * 512];   // 32 KB
    __shared__ float gpart[4][NI][NN];                    // 8 KB
    __shared__ float glds[NI][NN];                        // 2 KB
    __shared__ float red[2][4][2];

    // ---- stage E (frag-ordered, linear chunk ordering -> conflict-free)
    #pragma unroll
    for (int i = 0; i < NI; ++i) {
        const float* efb = ef + (size_t)(bi0 + i) * NN * ED;
        #pragma unroll
        for (int it = 0; it < 2; ++it) {
            const int c = it * 256 + t;                    // chunk 0..511
            const int j = ((c >> 6) << 4) | (c & 15);
            const int kb = ((c >> 4) & 3) * 8;
            const float* p = efb + j * ED + kb;
            f32x4 a0 = *(const f32x4*)p;
            f32x4 a1 = *(const f32x4*)(p + 4);
            sh8 v;
            v[0] = (short)f2bf(a0[0]); v[1] = (short)f2bf(a0[1]);
            v[2] = (short)f2bf(a0[2]); v[3] = (short)f2bf(a0[3]);
            v[4] = (short)f2bf(a1[0]); v[5] = (short)f2bf(a1[1]);
            v[6] = (short)f2bf(a1[2]); v[7] = (short)f2bf(a1[3]);
            *(sh8*)&Elds[i * 4096 + c * 8] = v;
        }
    }
    __syncthreads();

    const int kcol = w * 64 + col;
    sh8 Bg[4], Bm[4];
    #pragma unroll
    for (int n = 0; n < 4; ++n) {
        Bg[n] = *(const sh8*)&Bprep[(size_t)(w * 4 + n) * 512 + lane * 8];
        Bm[n] = *(const sh8*)&Bprep[(size_t)(16 + w * 4 + n) * 512 + lane * 8];
    }

    // ================= gate pass
    {
        float hgiR[NI][4], wg2R[4];
        #pragma unroll
        for (int n = 0; n < 4; ++n) wg2R[n] = Wg2[kcol + n * 16];
        #pragma unroll
        for (int i = 0; i < NI; ++i)
            #pragma unroll
            for (int n = 0; n < 4; ++n)
                hgiR[i][n] = Hgi[(size_t)(bi0 + i) * ID + kcol + n * 16];
        const float* HgjB = Hgj + (size_t)b * NN * ID;
        for (int s = 0; s < 8; ++s) {
            float hgj[4][4];
            #pragma unroll
            for (int n = 0; n < 4; ++n)
                #pragma unroll
                for (int r = 0; r < 4; ++r)
                    hgj[n][r] = HgjB[(size_t)(s * 16 + grp * 4 + r) * ID + kcol + n * 16];
            #pragma unroll
            for (int i = 0; i < NI; ++i) {
                sh8 Af = *(const sh8*)&Elds[i * 4096 + s * 512 + lane * 8];
                f32x4 acc[4];
                #pragma unroll
                for (int n = 0; n < 4; ++n)
                    acc[n] = __builtin_amdgcn_mfma_f32_16x16x32_bf16(
                        Af, Bg[n], (f32x4){0.f, 0.f, 0.f, 0.f}, 0, 0, 0);
                float p[4] = {0.f, 0.f, 0.f, 0.f};
                #pragma unroll
                for (int n = 0; n < 4; ++n)
                    #pragma unroll
                    for (int r = 0; r < 4; ++r)
                        p[r] = fmaf(ftanh(acc[n][r] + hgj[n][r] + hgiR[i][n]),
                                    wg2R[n], p[r]);
                #pragma unroll
                for (int m = 1; m < 16; m <<= 1)
                    #pragma unroll
                    for (int r = 0; r < 4; ++r) p[r] += __shfl_xor(p[r], m, 64);
                if (col == 0) {
                    #pragma unroll
                    for (int r = 0; r < 4; ++r)
                        gpart[w][i][s * 16 + grp * 4 + r] = p[r];
                }
            }
        }
    }
    __syncthreads();

    // ---- combine gate partials, sigmoid, gsum/deg reductions
    {
        const float bg2v = bg2[0];
        #pragma unroll
        for (int it = 0; it < NI / 2; ++it) {
            const int i = it * 2 + (t >> 7);
            const int j = t & 127;
            const float pre = gpart[0][i][j] + gpart[1][i][j] +
                              gpart[2][i][j] + gpart[3][i][j] + bg2v;
            const float m = em[(size_t)(bi0 + i) * NN + j];
            const float g = m * __builtin_amdgcn_rcpf(1.0f + __expf(-pre));
            glds[i][j] = g;
            float gsv = g, dv = m;
            #pragma unroll
            for (int mm = 1; mm < 64; mm <<= 1) {
                gsv += __shfl_xor(gsv, mm, 64);
                dv  += __shfl_xor(dv, mm, 64);
            }
            if (lane == 0) { red[it][w][0] = gsv; red[it][w][1] = dv; }
        }
    }
    __syncthreads();
    if (t < NI) {
        const int it = t >> 1, w0 = (t & 1) * 2;
        gsum[bi0 + t] = red[it][w0][0] + red[it][w0 + 1][0];
        deg[bi0 + t]  = red[it][w0][1] + red[it][w0 + 1][1];
    }

    // ================= msg pass
    {
        float hmiR[NI][4];
        #pragma unroll
        for (int i = 0; i < NI; ++i)
            #pragma unroll
            for (int n = 0; n < 4; ++n)
                hmiR[i][n] = Hmi[(size_t)(bi0 + i) * ID + kcol + n * 16];
        const float* HmjB = Hmj + (size_t)b * NN * ID;
        float ts[NI][4];
        #pragma unroll
        for (int i = 0; i < NI; ++i)
            #pragma unroll
            for (int n = 0; n < 4; ++n) ts[i][n] = 0.f;
        for (int s = 0; s < 8; ++s) {
            float hmj[4][4];
            #pragma unroll
            for (int n = 0; n < 4; ++n)
                #pragma unroll
                for (int r = 0; r < 4; ++r)
                    hmj[n][r] = HmjB[(size_t)(s * 16 + grp * 4 + r) * ID + kcol + n * 16];
            #pragma unroll
            for (int i = 0; i < NI; ++i) {
                sh8 Af = *(const sh8*)&Elds[i * 4096 + s * 512 + lane * 8];
                f32x4 acc[4];
                #pragma unroll
                for (int n = 0; n < 4; ++n)
                    acc[n] = __builtin_amdgcn_mfma_f32_16x16x32_bf16(
                        Af, Bm[n], (f32x4){0.f, 0.f, 0.f, 0.f}, 0, 0, 0);
                f32x4 gr = *(const f32x4*)&glds[i][s * 16 + grp * 4];
                #pragma unroll
                for (int n = 0; n < 4; ++n)
                    #pragma unroll
                    for (int r = 0; r < 4; ++r)
                        ts[i][n] = fmaf(gr[r],
                                        ftanh(acc[n][r] + hmj[n][r] + hmiR[i][n]),
                                        ts[i][n]);
            }
        }
        #pragma unroll
        for (int i = 0; i < NI; ++i)
            #pragma unroll
            for (int n = 0; n < 4; ++n) {
                ts[i][n] += __shfl_xor(ts[i][n], 16, 64);
                ts[i][n] += __shfl_xor(ts[i][n], 32, 64);
            }
        if (lane < 16) {
            #pragma unroll
            for (int i = 0; i < NI; ++i)
                #pragma unroll
                for (int n = 0; n < 4; ++n)
                    T[(size_t)(bi0 + i) * ID + kcol - col + n * 16 + lane] = ts[i][n];
        }
    }
}

// ---------------------------------------------------------------------------
// K34: fused agg (T@Wm2) -> update MLP -> residual -> LayerNorm, 8 rows/block
// grid BN/8, block 256
// ---------------------------------------------------------------------------
__global__ void k34_update(const float* __restrict__ T, const float* __restrict__ gsum,
                           const float* __restrict__ deg, const float* __restrict__ h,
                           const float* __restrict__ Wm2, const float* __restrict__ bm2,
                           const float* __restrict__ Wu1, const float* __restrict__ bu1,
                           const float* __restrict__ Wu2, const float* __restrict__ bu2,
                           const float* __restrict__ lnw, const float* __restrict__ lnb,
                           float* __restrict__ out) {
    const int tile = blockIdx.x;
    const int row0 = tile * 8;
    __shared__ float Ts[8][ID];
    __shared__ float up[8][2 * SD + 1];
    __shared__ float u[8][ID];
    __shared__ float xs[8][SD];
    __shared__ float gss[8];
    const int t = threadIdx.x;
    const float* Tb = T + (size_t)row0 * ID;
    for (int i = t; i < 8 * ID; i += 256) Ts[i >> 8][i & 255] = Tb[i];
    for (int i = t; i < 8 * SD; i += 256) up[i >> 7][i & 127] = h[(size_t)row0 * SD + i];
    if (t < 8) {
        gss[t] = gsum[row0 + t];
        up[t][2 * SD] = deg[row0 + t] * (1.0f / 127.0f);
    }
    __syncthreads();
    {   // agg -> up[r][128+d]
        const int d = t & 127;
        const int r0 = (t >> 7) * 4;
        float acc[4] = {0.f, 0.f, 0.f, 0.f};
        #pragma unroll 8
        for (int kk = 0; kk < ID; ++kk) {
            const float wv = Wm2[kk * SD + d];
            #pragma unroll
            for (int r = 0; r < 4; ++r) acc[r] = fmaf(Ts[r0 + r][kk], wv, acc[r]);
        }
        const float bmv = bm2[d];
        #pragma unroll
        for (int r = 0; r < 4; ++r) {
            const float g = gss[r0 + r];
            up[r0 + r][SD + d] = (acc[r] + g * bmv) *
                                 __builtin_amdgcn_rcpf(fmaxf(g, 1.0f));
        }
    }
    __syncthreads();
    {   // FC1 (257 -> 256) + tanh
        float acc[8];
        const float bk = bu1[t];
        #pragma unroll
        for (int r = 0; r < 8; ++r) acc[r] = bk;
        #pragma unroll 4
        for (int c = 0; c < 2 * SD + 1; ++c) {
            const float wv = Wu1[c * ID + t];
            #pragma unroll
            for (int r = 0; r < 8; ++r) acc[r] = fmaf(up[r][c], wv, acc[r]);
        }
        #pragma unroll
        for (int r = 0; r < 8; ++r) u[r][t] = ftanh(acc[r]);
    }
    __syncthreads();
    {   // FC2 (256 -> 128) + tanh + residual
        const int d = t & 127;
        const int r0 = (t >> 7) * 4;
        float acc[4];
        const float bd = bu2[d];
        #pragma unroll
        for (int r = 0; r < 4; ++r) acc[r] = bd;
        #pragma unroll 8
        for (int kk = 0; kk < ID; ++kk) {
            const float wv = Wu2[kk * SD + d];
            #pragma unroll
            for (int r = 0; r < 4; ++r) acc[r] = fmaf(u[r0 + r][kk], wv, acc[r]);
        }
        #pragma unroll
        for (int r = 0; r < 4; ++r) xs[r0 + r][d] = up[r0 + r][d] + ftanh(acc[r]);
    }
    __syncthreads();
    const int w = t >> 6, lane = t & 63;
    #pragma unroll
    for (int rr = 0; rr < 2; ++rr) {
        const int r = w * 2 + rr;
        const float v0 = xs[r][lane], v1 = xs[r][lane + 64];
        float s = v0 + v1;
        #pragma unroll
        for (int m = 1; m < 64; m <<= 1) s += __shfl_xor(s, m, 64);
        const float mu = s * (1.0f / SD);
        const float d0 = v0 - mu, d1 = v1 - mu;
        float q = d0 * d0 + d1 * d1;
        #pragma unroll
        for (int m = 1; m < 64; m <<= 1) q += __shfl_xor(q, m, 64);
        const float inv = rsqrtf(q * (1.0f / SD) + 1e-5f);
        out[(size_t)(row0 + r) * SD + lane] = d0 * inv * lnw[lane] + lnb[lane];
        out[(size_t)(row0 + r) * SD + lane + 64] = d1 * inv * lnw[lane + 64] + lnb[lane + 64];
    }
}

extern "C" void kernel_launch(void* const* d_in, const int* in_sizes, int n_in,
                              void* d_out, int out_size, void* d_ws, size_t ws_size,
                              hipStream_t stream) {
    const float* h   = (const float*)d_in[0];
    const float* ef  = (const float*)d_in[1];
    const float* em  = (const float*)d_in[2];
    const float* Wm1 = (const float*)d_in[3];
    const float* bm1 = (const float*)d_in[4];
    const float* Wm2 = (const float*)d_in[5];
    const float* bm2 = (const float*)d_in[6];
    const float* Wg1 = (const float*)d_in[7];
    const float* bg1 = (const float*)d_in[8];
    const float* Wg2 = (const float*)d_in[9];
    const float* bg2 = (const float*)d_in[10];
    const float* Wu1 = (const float*)d_in[11];
    const float* bu1 = (const float*)d_in[12];
    const float* Wu2 = (const float*)d_in[13];
    const float* bu2 = (const float*)d_in[14];
    const float* lnw = (const float*)d_in[15];
    const float* lnb = (const float*)d_in[16];

    float* ws = (float*)d_ws;
    float* Hgi   = ws;
    float* Hgj   = Hgi + (size_t)BN * ID;
    float* Hmi   = Hgj + (size_t)BN * ID;
    float* Hmj   = Hmi + (size_t)BN * ID;
    float* T     = Hmj + (size_t)BN * ID;
    float* gsumv = T + (size_t)BN * ID;
    float* degv  = gsumv + BN;
    ushort* Bprep = (ushort*)(degv + BN);
    float* outp = (float*)d_out;

    k_prep_w<<<32, 64, 0, stream>>>(Wg1, Wm1, Bprep);
    k1_preproj<<<dim3(BN / 32, 4), 256, 0, stream>>>(h, Wg1, bg1, Wm1, bm1,
                                                     Hgi, Hgj, Hmi, Hmj);
    k2_edges<<<BN / NI, 256, 0, stream>>>(ef, em, Bprep, Hgi, Hmi, Hgj, Hmj,
                                          Wg2, bg2, T, gsumv, degv);
    k34_update<<<BN / 8, 256, 0, stream>>>(T, gsumv, degv, h, Wm2, bm2,
                                           Wu1, bu1, Wu2, bu2, lnw, lnb, outp);
}

// Round 4
// 195.302 us; speedup vs baseline: 1.8213x; 1.8213x over previous
//
#include <hip/hip_runtime.h>
#include <hip/hip_bf16.h>

#define BB 32
#define NN 128
#define SD 128
#define ED 32
#define ID 256
#define BN (BB*NN)   // 4096
#define NI 4         // i-blocks per k2 workgroup

typedef __attribute__((ext_vector_type(8))) short sh8;
typedef __attribute__((ext_vector_type(4))) float f32x4;

__device__ __forceinline__ float ftanh(float x) {
    float e2 = __expf(2.0f * x);
    return 1.0f - 2.0f * __builtin_amdgcn_rcpf(e2 + 1.0f);
}

__device__ __forceinline__ ushort f2bf(float f) {
    unsigned u = __float_as_uint(f);
    return (ushort)((u + 0x7FFF + ((u >> 16) & 1)) >> 16);
}

// ---------------------------------------------------------------------------
// prep: B-fragments of We = W1[256:288, :] (K=32), bf16, frag-ordered.
// grid 32, block 64
// ---------------------------------------------------------------------------
__global__ void k_prep_w(const float* __restrict__ Wg1, const float* __restrict__ Wm1,
                         ushort* __restrict__ Bprep) {
    const int tile = blockIdx.x;
    const int l = threadIdx.x;
    const int mat = tile >> 4;
    const int nt = tile & 15;
    const float* W = mat ? Wm1 : Wg1;
    const int col = nt * 16 + (l & 15);
    const int kbase = (l >> 4) * 8;
    sh8 v;
    #pragma unroll
    for (int e = 0; e < 8; ++e)
        v[e] = (short)f2bf(W[(size_t)(2 * SD + kbase + e) * ID + col]);
    *(sh8*)&Bprep[(size_t)tile * 512 + l * 8] = v;
}

// ---------------------------------------------------------------------------
// K1: node projections (f32, exact). 16 rows/block, acc[16] -> no spill.
// which 0: Hgi = h@Wg1[0:128]+bg1   1: Hgj = h@Wg1[128:256]
//       2: Hmi = h@Wm1[0:128]+bm1   3: Hmj = h@Wm1[128:256]
// grid (BN/16, 4), block 256
// ---------------------------------------------------------------------------
__global__ void k1_preproj(const float* __restrict__ h,
                           const float* __restrict__ Wg1, const float* __restrict__ bg1,
                           const float* __restrict__ Wm1, const float* __restrict__ bm1,
                           float* __restrict__ Hgi, float* __restrict__ Hgj,
                           float* __restrict__ Hmi, float* __restrict__ Hmj) {
    const int tile = blockIdx.x;
    const int which = blockIdx.y;
    __shared__ float hs[16][SD];
    const int t = threadIdx.x;
    const float* hrow = h + (size_t)tile * 16 * SD;
    for (int i = t; i < 16 * SD; i += 256) hs[i >> 7][i & 127] = hrow[i];
    __syncthreads();
    const float* W; const float* bias = nullptr; float* out;
    if (which == 0)      { W = Wg1;           bias = bg1; out = Hgi; }
    else if (which == 1) { W = Wg1 + SD * ID;             out = Hgj; }
    else if (which == 2) { W = Wm1;           bias = bm1; out = Hmi; }
    else                 { W = Wm1 + SD * ID;             out = Hmj; }
    const int k = t;
    float acc[16];
    const float b0 = bias ? bias[k] : 0.0f;
    #pragma unroll
    for (int r = 0; r < 16; ++r) acc[r] = b0;
    for (int c = 0; c < SD; ++c) {
        const float wv = W[c * ID + k];
        #pragma unroll
        for (int r = 0; r < 16; ++r) acc[r] = fmaf(hs[r][c], wv, acc[r]);
    }
    #pragma unroll
    for (int r = 0; r < 16; ++r) out[(size_t)(tile * 16 + r) * ID + k] = acc[r];
}

// ---------------------------------------------------------------------------
// K2: NI consecutive i's of one b per block. E-proj via MFMA (K=32, bf16),
// + f32 Hgi[k] + Hgj[j,k] (global, L2-hit, amortized over NI).
// grid BN/NI, block 256
// ---------------------------------------------------------------------------
__global__ __launch_bounds__(256, 3) void k2_edges(
        const float* __restrict__ ef, const float* __restrict__ em,
        const ushort* __restrict__ Bprep,
        const float* __restrict__ Hgi, const float* __restrict__ Hmi,
        const float* __restrict__ Hgj, const float* __restrict__ Hmj,
        const float* __restrict__ Wg2, const float* __restrict__ bg2,
        float* __restrict__ T, float* __restrict__ gsum, float* __restrict__ deg) {
    const int bi0 = blockIdx.x * NI;
    const int b = bi0 >> 7;
    const int t = threadIdx.x;
    const int w = t >> 6;
    const int lane = t & 63;
    const int col = lane & 15;
    const int grp = lane >> 4;

    __shared__ __align__(16) ushort Elds[NI * 8 * 512];   // 32 KB
    __shared__ float gpart[4][NI][NN];                    // 8 KB
    __shared__ float glds[NI][NN];                        // 2 KB
    __shared__ float red[2][4][2];

    // ---- stage E (frag-ordered, linear chunk ordering -> conflict-free)
    #pragma unroll
    for (int i = 0; i < NI; ++i) {
        const float* efb = ef + (size_t)(bi0 + i) * NN * ED;
        #pragma unroll
        for (int it = 0; it < 2; ++it) {
            const int c = it * 256 + t;                    // chunk 0..511
            const int j = ((c >> 6) << 4) | (c & 15);
            const int kb = ((c >> 4) & 3) * 8;
            const float* p = efb + j * ED + kb;
            f32x4 a0 = *(const f32x4*)p;
            f32x4 a1 = *(const f32x4*)(p + 4);
            sh8 v;
            v[0] = (short)f2bf(a0[0]); v[1] = (short)f2bf(a0[1]);
            v[2] = (short)f2bf(a0[2]); v[3] = (short)f2bf(a0[3]);
            v[4] = (short)f2bf(a1[0]); v[5] = (short)f2bf(a1[1]);
            v[6] = (short)f2bf(a1[2]); v[7] = (short)f2bf(a1[3]);
            *(sh8*)&Elds[i * 4096 + c * 8] = v;
        }
    }
    __syncthreads();

    const int kcol = w * 64 + col;
    sh8 Bg[4], Bm[4];
    #pragma unroll
    for (int n = 0; n < 4; ++n) {
        Bg[n] = *(const sh8*)&Bprep[(size_t)(w * 4 + n) * 512 + lane * 8];
        Bm[n] = *(const sh8*)&Bprep[(size_t)(16 + w * 4 + n) * 512 + lane * 8];
    }

    // ================= gate pass
    {
        float hgiR[NI][4], wg2R[4];
        #pragma unroll
        for (int n = 0; n < 4; ++n) wg2R[n] = Wg2[kcol + n * 16];
        #pragma unroll
        for (int i = 0; i < NI; ++i)
            #pragma unroll
            for (int n = 0; n < 4; ++n)
                hgiR[i][n] = Hgi[(size_t)(bi0 + i) * ID + kcol + n * 16];
        const float* HgjB = Hgj + (size_t)b * NN * ID;
        for (int s = 0; s < 8; ++s) {
            float hgj[4][4];
            #pragma unroll
            for (int n = 0; n < 4; ++n)
                #pragma unroll
                for (int r = 0; r < 4; ++r)
                    hgj[n][r] = HgjB[(size_t)(s * 16 + grp * 4 + r) * ID + kcol + n * 16];
            #pragma unroll
            for (int i = 0; i < NI; ++i) {
                sh8 Af = *(const sh8*)&Elds[i * 4096 + s * 512 + lane * 8];
                f32x4 acc[4];
                #pragma unroll
                for (int n = 0; n < 4; ++n)
                    acc[n] = __builtin_amdgcn_mfma_f32_16x16x32_bf16(
                        Af, Bg[n], (f32x4){0.f, 0.f, 0.f, 0.f}, 0, 0, 0);
                float p[4] = {0.f, 0.f, 0.f, 0.f};
                #pragma unroll
                for (int n = 0; n < 4; ++n)
                    #pragma unroll
                    for (int r = 0; r < 4; ++r)
                        p[r] = fmaf(ftanh(acc[n][r] + hgj[n][r] + hgiR[i][n]),
                                    wg2R[n], p[r]);
                #pragma unroll
                for (int m = 1; m < 16; m <<= 1)
                    #pragma unroll
                    for (int r = 0; r < 4; ++r) p[r] += __shfl_xor(p[r], m, 64);
                if (col == 0) {
                    #pragma unroll
                    for (int r = 0; r < 4; ++r)
                        gpart[w][i][s * 16 + grp * 4 + r] = p[r];
                }
            }
        }
    }
    __syncthreads();

    // ---- combine gate partials, sigmoid, gsum/deg reductions
    {
        const float bg2v = bg2[0];
        #pragma unroll
        for (int it = 0; it < NI / 2; ++it) {
            const int i = it * 2 + (t >> 7);
            const int j = t & 127;
            const float pre = gpart[0][i][j] + gpart[1][i][j] +
                              gpart[2][i][j] + gpart[3][i][j] + bg2v;
            const float m = em[(size_t)(bi0 + i) * NN + j];
            const float g = m * __builtin_amdgcn_rcpf(1.0f + __expf(-pre));
            glds[i][j] = g;
            float gsv = g, dv = m;
            #pragma unroll
            for (int mm = 1; mm < 64; mm <<= 1) {
                gsv += __shfl_xor(gsv, mm, 64);
                dv  += __shfl_xor(dv, mm, 64);
            }
            if (lane == 0) { red[it][w][0] = gsv; red[it][w][1] = dv; }
        }
    }
    __syncthreads();
    if (t < NI) {
        const int it = t >> 1, w0 = (t & 1) * 2;
        gsum[bi0 + t] = red[it][w0][0] + red[it][w0 + 1][0];
        deg[bi0 + t]  = red[it][w0][1] + red[it][w0 + 1][1];
    }

    // ================= msg pass
    {
        float hmiR[NI][4];
        #pragma unroll
        for (int i = 0; i < NI; ++i)
            #pragma unroll
            for (int n = 0; n < 4; ++n)
                hmiR[i][n] = Hmi[(size_t)(bi0 + i) * ID + kcol + n * 16];
        const float* HmjB = Hmj + (size_t)b * NN * ID;
        float ts[NI][4];
        #pragma unroll
        for (int i = 0; i < NI; ++i)
            #pragma unroll
            for (int n = 0; n < 4; ++n) ts[i][n] = 0.f;
        for (int s = 0; s < 8; ++s) {
            float hmj[4][4];
            #pragma unroll
            for (int n = 0; n < 4; ++n)
                #pragma unroll
                for (int r = 0; r < 4; ++r)
                    hmj[n][r] = HmjB[(size_t)(s * 16 + grp * 4 + r) * ID + kcol + n * 16];
            #pragma unroll
            for (int i = 0; i < NI; ++i) {
                sh8 Af = *(const sh8*)&Elds[i * 4096 + s * 512 + lane * 8];
                f32x4 acc[4];
                #pragma unroll
                for (int n = 0; n < 4; ++n)
                    acc[n] = __builtin_amdgcn_mfma_f32_16x16x32_bf16(
                        Af, Bm[n], (f32x4){0.f, 0.f, 0.f, 0.f}, 0, 0, 0);
                f32x4 gr = *(const f32x4*)&glds[i][s * 16 + grp * 4];
                #pragma unroll
                for (int n = 0; n < 4; ++n)
                    #pragma unroll
                    for (int r = 0; r < 4; ++r)
                        ts[i][n] = fmaf(gr[r],
                                        ftanh(acc[n][r] + hmj[n][r] + hmiR[i][n]),
                                        ts[i][n]);
            }
        }
        #pragma unroll
        for (int i = 0; i < NI; ++i)
            #pragma unroll
            for (int n = 0; n < 4; ++n) {
                ts[i][n] += __shfl_xor(ts[i][n], 16, 64);
                ts[i][n] += __shfl_xor(ts[i][n], 32, 64);
            }
        if (lane < 16) {
            #pragma unroll
            for (int i = 0; i < NI; ++i)
                #pragma unroll
                for (int n = 0; n < 4; ++n)
                    T[(size_t)(bi0 + i) * ID + kcol - col + n * 16 + lane] = ts[i][n];
        }
    }
}

// ---------------------------------------------------------------------------
// K34: fused agg (T@Wm2) -> update MLP -> residual -> LayerNorm, 8 rows/block
// grid BN/8, block 256
// ---------------------------------------------------------------------------
__global__ void k34_update(const float* __restrict__ T, const float* __restrict__ gsum,
                           const float* __restrict__ deg, const float* __restrict__ h,
                           const float* __restrict__ Wm2, const float* __restrict__ bm2,
                           const float* __restrict__ Wu1, const float* __restrict__ bu1,
                           const float* __restrict__ Wu2, const float* __restrict__ bu2,
                           const float* __restrict__ lnw, const float* __restrict__ lnb,
                           float* __restrict__ out) {
    const int tile = blockIdx.x;
    const int row0 = tile * 8;
    __shared__ float Ts[8][ID];
    __shared__ float up[8][2 * SD + 1];
    __shared__ float u[8][ID];
    __shared__ float xs[8][SD];
    __shared__ float gss[8];
    const int t = threadIdx.x;
    const float* Tb = T + (size_t)row0 * ID;
    for (int i = t; i < 8 * ID; i += 256) Ts[i >> 8][i & 255] = Tb[i];
    for (int i = t; i < 8 * SD; i += 256) up[i >> 7][i & 127] = h[(size_t)row0 * SD + i];
    if (t < 8) {
        gss[t] = gsum[row0 + t];
        up[t][2 * SD] = deg[row0 + t] * (1.0f / 127.0f);
    }
    __syncthreads();
    {   // agg -> up[r][128+d]
        const int d = t & 127;
        const int r0 = (t >> 7) * 4;
        float acc[4] = {0.f, 0.f, 0.f, 0.f};
        for (int kk = 0; kk < ID; ++kk) {
            const float wv = Wm2[kk * SD + d];
            #pragma unroll
            for (int r = 0; r < 4; ++r) acc[r] = fmaf(Ts[r0 + r][kk], wv, acc[r]);
        }
        const float bmv = bm2[d];
        #pragma unroll
        for (int r = 0; r < 4; ++r) {
            const float g = gss[r0 + r];
            up[r0 + r][SD + d] = (acc[r] + g * bmv) *
                                 __builtin_amdgcn_rcpf(fmaxf(g, 1.0f));
        }
    }
    __syncthreads();
    {   // FC1 (257 -> 256) + tanh
        float acc[8];
        const float bk = bu1[t];
        #pragma unroll
        for (int r = 0; r < 8; ++r) acc[r] = bk;
        for (int c = 0; c < 2 * SD + 1; ++c) {
            const float wv = Wu1[c * ID + t];
            #pragma unroll
            for (int r = 0; r < 8; ++r) acc[r] = fmaf(up[r][c], wv, acc[r]);
        }
        #pragma unroll
        for (int r = 0; r < 8; ++r) u[r][t] = ftanh(acc[r]);
    }
    __syncthreads();
    {   // FC2 (256 -> 128) + tanh + residual
        const int d = t & 127;
        const int r0 = (t >> 7) * 4;
        float acc[4];
        const float bd = bu2[d];
        #pragma unroll
        for (int r = 0; r < 4; ++r) acc[r] = bd;
        for (int kk = 0; kk < ID; ++kk) {
            const float wv = Wu2[kk * SD + d];
            #pragma unroll
            for (int r = 0; r < 4; ++r) acc[r] = fmaf(u[r0 + r][kk], wv, acc[r]);
        }
        #pragma unroll
        for (int r = 0; r < 4; ++r) xs[r0 + r][d] = up[r0 + r][d] + ftanh(acc[r]);
    }
    __syncthreads();
    const int w = t >> 6, lane = t & 63;
    #pragma unroll
    for (int rr = 0; rr < 2; ++rr) {
        const int r = w * 2 + rr;
        const float v0 = xs[r][lane], v1 = xs[r][lane + 64];
        float s = v0 + v1;
        #pragma unroll
        for (int m = 1; m < 64; m <<= 1) s += __shfl_xor(s, m, 64);
        const float mu = s * (1.0f / SD);
        const float d0 = v0 - mu, d1 = v1 - mu;
        float q = d0 * d0 + d1 * d1;
        #pragma unroll
        for (int m = 1; m < 64; m <<= 1) q += __shfl_xor(q, m, 64);
        const float inv = rsqrtf(q * (1.0f / SD) + 1e-5f);
        out[(size_t)(row0 + r) * SD + lane] = d0 * inv * lnw[lane] + lnb[lane];
        out[(size_t)(row0 + r) * SD + lane + 64] = d1 * inv * lnw[lane + 64] + lnb[lane + 64];
    }
}

extern "C" void kernel_launch(void* const* d_in, const int* in_sizes, int n_in,
                              void* d_out, int out_size, void* d_ws, size_t ws_size,
                              hipStream_t stream) {
    const float* h   = (const float*)d_in[0];
    const float* ef  = (const float*)d_in[1];
    const float* em  = (const float*)d_in[2];
    const float* Wm1 = (const float*)d_in[3];
    const float* bm1 = (const float*)d_in[4];
    const float* Wm2 = (const float*)d_in[5];
    const float* bm2 = (const float*)d_in[6];
    const float* Wg1 = (const float*)d_in[7];
    const float* bg1 = (const float*)d_in[8];
    const float* Wg2 = (const float*)d_in[9];
    const float* bg2 = (const float*)d_in[10];
    const float* Wu1 = (const float*)d_in[11];
    const float* bu1 = (const float*)d_in[12];
    const float* Wu2 = (const float*)d_in[13];
    const float* bu2 = (const float*)d_in[14];
    const float* lnw = (const float*)d_in[15];
    const float* lnb = (const float*)d_in[16];

    float* ws = (float*)d_ws;
    float* Hgi   = ws;
    float* Hgj   = Hgi + (size_t)BN * ID;
    float* Hmi   = Hgj + (size_t)BN * ID;
    float* Hmj   = Hmi + (size_t)BN * ID;
    float* T     = Hmj + (size_t)BN * ID;
    float* gsumv = T + (size_t)BN * ID;
    float* degv  = gsumv + BN;
    ushort* Bprep = (ushort*)(degv + BN);
    float* outp = (float*)d_out;

    k_prep_w<<<32, 64, 0, stream>>>(Wg1, Wm1, Bprep);
    k1_preproj<<<dim3(BN / 16, 4), 256, 0, stream>>>(h, Wg1, bg1, Wm1, bm1,
                                                     Hgi, Hgj, Hmi, Hmj);
    k2_edges<<<BN / NI, 256, 0, stream>>>(ef, em, Bprep, Hgi, Hmi, Hgj, Hmj,
                                          Wg2, bg2, T, gsumv, degv);
    k34_update<<<BN / 8, 256, 0, stream>>>(T, gsumv, degv, h, Wm2, bm2,
                                           Wu1, bu1, Wu2, bu2, lnw, lnb, outp);
}

// Round 5
// 184.153 us; speedup vs baseline: 1.9316x; 1.0605x over previous
//
#include <hip/hip_runtime.h>
#include <hip/hip_bf16.h>

#define BB 32
#define NN 128
#define SD 128
#define ED 32
#define ID 256
#define BN (BB*NN)   // 4096
#define NI 4         // i-blocks per k2 workgroup

typedef __attribute__((ext_vector_type(8))) short sh8;
typedef __attribute__((ext_vector_type(4))) float f32x4;

__device__ __forceinline__ float ftanh(float x) {
    float e2 = __expf(2.0f * x);
    return 1.0f - 2.0f * __builtin_amdgcn_rcpf(e2 + 1.0f);
}

__device__ __forceinline__ ushort f2bf(float f) {
    unsigned u = __float_as_uint(f);
    return (ushort)((u + 0x7FFF + ((u >> 16) & 1)) >> 16);
}

// ---------------------------------------------------------------------------
// prep: B-fragments of We = W1[256:288, :] (K=32), bf16, frag-ordered.
// grid 32, block 64
// ---------------------------------------------------------------------------
__global__ void k_prep_w(const float* __restrict__ Wg1, const float* __restrict__ Wm1,
                         ushort* __restrict__ Bprep) {
    const int tile = blockIdx.x;
    const int l = threadIdx.x;
    const int mat = tile >> 4;
    const int nt = tile & 15;
    const float* W = mat ? Wm1 : Wg1;
    const int col = nt * 16 + (l & 15);
    const int kbase = (l >> 4) * 8;
    sh8 v;
    #pragma unroll
    for (int e = 0; e < 8; ++e)
        v[e] = (short)f2bf(W[(size_t)(2 * SD + kbase + e) * ID + col]);
    *(sh8*)&Bprep[(size_t)tile * 512 + l * 8] = v;
}

// ---------------------------------------------------------------------------
// K1: node projections (f32, exact). 16 rows = one (b,s) stripe per block.
// which 0: Hgi (normal layout, +bg1)   1: Hgjt (MFMA-C frag tiles)
//       2: Hmi (normal layout, +bm1)   3: Hmjt (MFMA-C frag tiles)
// Hxjt layout: [(tile*256 + col)*16 + r], tile = b*8+s, r = row within stripe.
// grid (BN/16, 4), block 256
// ---------------------------------------------------------------------------
__global__ void k1_preproj(const float* __restrict__ h,
                           const float* __restrict__ Wg1, const float* __restrict__ bg1,
                           const float* __restrict__ Wm1, const float* __restrict__ bm1,
                           float* __restrict__ Hgi, float* __restrict__ Hgjt,
                           float* __restrict__ Hmi, float* __restrict__ Hmjt) {
    const int tile = blockIdx.x;
    const int which = blockIdx.y;
    __shared__ float hs[16][SD];
    const int t = threadIdx.x;
    const float* hrow = h + (size_t)tile * 16 * SD;
    for (int i = t; i < 16 * SD; i += 256) hs[i >> 7][i & 127] = hrow[i];
    __syncthreads();
    const float* W; const float* bias = nullptr; float* out;
    if (which == 0)      { W = Wg1;           bias = bg1; out = Hgi; }
    else if (which == 1) { W = Wg1 + SD * ID;             out = Hgjt; }
    else if (which == 2) { W = Wm1;           bias = bm1; out = Hmi; }
    else                 { W = Wm1 + SD * ID;             out = Hmjt; }
    const int k = t;
    float acc[16];
    const float b0 = bias ? bias[k] : 0.0f;
    #pragma unroll
    for (int r = 0; r < 16; ++r) acc[r] = b0;
    for (int c = 0; c < SD; ++c) {
        const float wv = W[c * ID + k];
        #pragma unroll
        for (int r = 0; r < 16; ++r) acc[r] = fmaf(hs[r][c], wv, acc[r]);
    }
    if (which & 1) {
        #pragma unroll
        for (int r = 0; r < 16; ++r) out[((size_t)tile * ID + k) * 16 + r] = acc[r];
    } else {
        #pragma unroll
        for (int r = 0; r < 16; ++r) out[(size_t)(tile * 16 + r) * ID + k] = acc[r];
    }
}

// ---------------------------------------------------------------------------
// K2: NI consecutive i's of one b per block. E-proj via MFMA (K=32, bf16)
// with Hxjt frag tiles fed as the MFMA C operand (1 dwordx4/quadrant,
// double-buffered over s). Gate reduction via LDS atomicAdd.
// grid BN/NI, block 256
// ---------------------------------------------------------------------------
__global__ __launch_bounds__(256, 4) void k2_edges(
        const float* __restrict__ ef, const float* __restrict__ em,
        const ushort* __restrict__ Bprep,
        const float* __restrict__ Hgi, const float* __restrict__ Hmi,
        const float* __restrict__ Hgjt, const float* __restrict__ Hmjt,
        const float* __restrict__ Wg2, const float* __restrict__ bg2,
        float* __restrict__ T, float* __restrict__ gsum, float* __restrict__ deg) {
    const int bi0 = blockIdx.x * NI;
    const int b = bi0 >> 7;
    const int t = threadIdx.x;
    const int w = t >> 6;
    const int lane = t & 63;
    const int col = lane & 15;
    const int grp = lane >> 4;

    __shared__ __align__(16) ushort Elds[NI * 8 * 512];   // 32 KB
    __shared__ float glds[NI][NN];                        // 2 KB
    __shared__ float red[2][4][2];

    // ---- stage E (frag-ordered, linear chunk ordering -> conflict-free)
    // ---- and zero glds
    {
        float* gl = &glds[0][0];
        gl[t] = 0.f;
        gl[t + 256] = 0.f;
    }
    #pragma unroll
    for (int i = 0; i < NI; ++i) {
        const float* efb = ef + (size_t)(bi0 + i) * NN * ED;
        #pragma unroll
        for (int it = 0; it < 2; ++it) {
            const int c = it * 256 + t;                    // chunk 0..511
            const int j = ((c >> 6) << 4) | (c & 15);
            const int kb = ((c >> 4) & 3) * 8;
            const float* p = efb + j * ED + kb;
            f32x4 a0 = *(const f32x4*)p;
            f32x4 a1 = *(const f32x4*)(p + 4);
            sh8 v;
            v[0] = (short)f2bf(a0[0]); v[1] = (short)f2bf(a0[1]);
            v[2] = (short)f2bf(a0[2]); v[3] = (short)f2bf(a0[3]);
            v[4] = (short)f2bf(a1[0]); v[5] = (short)f2bf(a1[1]);
            v[6] = (short)f2bf(a1[2]); v[7] = (short)f2bf(a1[3]);
            *(sh8*)&Elds[i * 4096 + c * 8] = v;
        }
    }
    __syncthreads();

    const int kcol = w * 64 + col;
    sh8 Bg[4], Bm[4];
    #pragma unroll
    for (int n = 0; n < 4; ++n) {
        Bg[n] = *(const sh8*)&Bprep[(size_t)(w * 4 + n) * 512 + lane * 8];
        Bm[n] = *(const sh8*)&Bprep[(size_t)(16 + w * 4 + n) * 512 + lane * 8];
    }
    // per-lane base into the frag-tile array for this b: + (s*256 + kcol)*16 + grp*4
    const float* HgjL = Hgjt + (size_t)b * 8 * ID * 16 + (size_t)kcol * 16 + grp * 4;
    const float* HmjL = Hmjt + (size_t)b * 8 * ID * 16 + (size_t)kcol * 16 + grp * 4;

    // ================= gate pass
    {
        float hgiR[NI][4], wg2R[4];
        #pragma unroll
        for (int n = 0; n < 4; ++n) wg2R[n] = Wg2[kcol + n * 16];
        #pragma unroll
        for (int i = 0; i < NI; ++i)
            #pragma unroll
            for (int n = 0; n < 4; ++n)
                hgiR[i][n] = Hgi[(size_t)(bi0 + i) * ID + kcol + n * 16];
        f32x4 Cg[4], Cn[4];
        #pragma unroll
        for (int n = 0; n < 4; ++n) Cg[n] = *(const f32x4*)(HgjL + n * 256);
        for (int s = 0; s < 8; ++s) {
            if (s < 7) {
                const float* ps = HgjL + (s + 1) * (ID * 16);
                #pragma unroll
                for (int n = 0; n < 4; ++n) Cn[n] = *(const f32x4*)(ps + n * 256);
            }
            #pragma unroll
            for (int i = 0; i < NI; ++i) {
                sh8 Af = *(const sh8*)&Elds[i * 4096 + s * 512 + lane * 8];
                f32x4 acc[4];
                #pragma unroll
                for (int n = 0; n < 4; ++n)
                    acc[n] = __builtin_amdgcn_mfma_f32_16x16x32_bf16(
                        Af, Bg[n], Cg[n], 0, 0, 0);
                float p[4] = {0.f, 0.f, 0.f, 0.f};
                #pragma unroll
                for (int n = 0; n < 4; ++n)
                    #pragma unroll
                    for (int r = 0; r < 4; ++r)
                        p[r] = fmaf(ftanh(acc[n][r] + hgiR[i][n]), wg2R[n], p[r]);
                #pragma unroll
                for (int m = 1; m < 16; m <<= 1)
                    #pragma unroll
                    for (int r = 0; r < 4; ++r) p[r] += __shfl_xor(p[r], m, 64);
                if (col == 0) {
                    #pragma unroll
                    for (int r = 0; r < 4; ++r)
                        atomicAdd(&glds[i][s * 16 + grp * 4 + r], p[r]);
                }
            }
            #pragma unroll
            for (int n = 0; n < 4; ++n) Cg[n] = Cn[n];
        }
    }
    __syncthreads();

    // ---- sigmoid + mask, gsum/deg reductions
    {
        const float bg2v = bg2[0];
        #pragma unroll
        for (int it = 0; it < NI / 2; ++it) {
            const int i = it * 2 + (t >> 7);
            const int j = t & 127;
            const float pre = glds[i][j] + bg2v;
            const float m = em[(size_t)(bi0 + i) * NN + j];
            const float g = m * __builtin_amdgcn_rcpf(1.0f + __expf(-pre));
            glds[i][j] = g;
            float gsv = g, dv = m;
            #pragma unroll
            for (int mm = 1; mm < 64; mm <<= 1) {
                gsv += __shfl_xor(gsv, mm, 64);
                dv  += __shfl_xor(dv, mm, 64);
            }
            if (lane == 0) { red[it][w][0] = gsv; red[it][w][1] = dv; }
        }
    }
    __syncthreads();
    if (t < NI) {
        const int it = t >> 1, w0 = (t & 1) * 2;
        gsum[bi0 + t] = red[it][w0][0] + red[it][w0 + 1][0];
        deg[bi0 + t]  = red[it][w0][1] + red[it][w0 + 1][1];
    }

    // ================= msg pass
    {
        float hmiR[NI][4];
        #pragma unroll
        for (int i = 0; i < NI; ++i)
            #pragma unroll
            for (int n = 0; n < 4; ++n)
                hmiR[i][n] = Hmi[(size_t)(bi0 + i) * ID + kcol + n * 16];
        float ts[NI][4];
        #pragma unroll
        for (int i = 0; i < NI; ++i)
            #pragma unroll
            for (int n = 0; n < 4; ++n) ts[i][n] = 0.f;
        f32x4 Cm[4], Cn[4];
        #pragma unroll
        for (int n = 0; n < 4; ++n) Cm[n] = *(const f32x4*)(HmjL + n * 256);
        for (int s = 0; s < 8; ++s) {
            if (s < 7) {
                const float* ps = HmjL + (s + 1) * (ID * 16);
                #pragma unroll
                for (int n = 0; n < 4; ++n) Cn[n] = *(const f32x4*)(ps + n * 256);
            }
            #pragma unroll
            for (int i = 0; i < NI; ++i) {
                sh8 Af = *(const sh8*)&Elds[i * 4096 + s * 512 + lane * 8];
                f32x4 acc[4];
                #pragma unroll
                for (int n = 0; n < 4; ++n)
                    acc[n] = __builtin_amdgcn_mfma_f32_16x16x32_bf16(
                        Af, Bm[n], Cm[n], 0, 0, 0);
                f32x4 gr = *(const f32x4*)&glds[i][s * 16 + grp * 4];
                #pragma unroll
                for (int n = 0; n < 4; ++n)
                    #pragma unroll
                    for (int r = 0; r < 4; ++r)
                        ts[i][n] = fmaf(gr[r], ftanh(acc[n][r] + hmiR[i][n]),
                                        ts[i][n]);
            }
            #pragma unroll
            for (int n = 0; n < 4; ++n) Cm[n] = Cn[n];
        }
        #pragma unroll
        for (int i = 0; i < NI; ++i)
            #pragma unroll
            for (int n = 0; n < 4; ++n) {
                ts[i][n] += __shfl_xor(ts[i][n], 16, 64);
                ts[i][n] += __shfl_xor(ts[i][n], 32, 64);
            }
        if (lane < 16) {
            #pragma unroll
            for (int i = 0; i < NI; ++i)
                #pragma unroll
                for (int n = 0; n < 4; ++n)
                    T[(size_t)(bi0 + i) * ID + kcol - col + n * 16 + lane] = ts[i][n];
        }
    }
}

// ---------------------------------------------------------------------------
// K34: fused agg (T@Wm2) -> update MLP -> residual -> LayerNorm, 8 rows/block
// grid BN/8, block 256
// ---------------------------------------------------------------------------
__global__ void k34_update(const float* __restrict__ T, const float* __restrict__ gsum,
                           const float* __restrict__ deg, const float* __restrict__ h,
                           const float* __restrict__ Wm2, const float* __restrict__ bm2,
                           const float* __restrict__ Wu1, const float* __restrict__ bu1,
                           const float* __restrict__ Wu2, const float* __restrict__ bu2,
                           const float* __restrict__ lnw, const float* __restrict__ lnb,
                           float* __restrict__ out) {
    const int tile = blockIdx.x;
    const int row0 = tile * 8;
    __shared__ float Ts[8][ID];
    __shared__ float up[8][2 * SD + 1];
    __shared__ float u[8][ID];
    __shared__ float xs[8][SD];
    __shared__ float gss[8];
    const int t = threadIdx.x;
    const float* Tb = T + (size_t)row0 * ID;
    for (int i = t; i < 8 * ID; i += 256) Ts[i >> 8][i & 255] = Tb[i];
    for (int i = t; i < 8 * SD; i += 256) up[i >> 7][i & 127] = h[(size_t)row0 * SD + i];
    if (t < 8) {
        gss[t] = gsum[row0 + t];
        up[t][2 * SD] = deg[row0 + t] * (1.0f / 127.0f);
    }
    __syncthreads();
    {   // agg -> up[r][128+d]
        const int d = t & 127;
        const int r0 = (t >> 7) * 4;
        float acc[4] = {0.f, 0.f, 0.f, 0.f};
        for (int kk = 0; kk < ID; ++kk) {
            const float wv = Wm2[kk * SD + d];
            #pragma unroll
            for (int r = 0; r < 4; ++r) acc[r] = fmaf(Ts[r0 + r][kk], wv, acc[r]);
        }
        const float bmv = bm2[d];
        #pragma unroll
        for (int r = 0; r < 4; ++r) {
            const float g = gss[r0 + r];
            up[r0 + r][SD + d] = (acc[r] + g * bmv) *
                                 __builtin_amdgcn_rcpf(fmaxf(g, 1.0f));
        }
    }
    __syncthreads();
    {   // FC1 (257 -> 256) + tanh
        float acc[8];
        const float bk = bu1[t];
        #pragma unroll
        for (int r = 0; r < 8; ++r) acc[r] = bk;
        for (int c = 0; c < 2 * SD + 1; ++c) {
            const float wv = Wu1[c * ID + t];
            #pragma unroll
            for (int r = 0; r < 8; ++r) acc[r] = fmaf(up[r][c], wv, acc[r]);
        }
        #pragma unroll
        for (int r = 0; r < 8; ++r) u[r][t] = ftanh(acc[r]);
    }
    __syncthreads();
    {   // FC2 (256 -> 128) + tanh + residual
        const int d = t & 127;
        const int r0 = (t >> 7) * 4;
        float acc[4];
        const float bd = bu2[d];
        #pragma unroll
        for (int r = 0; r < 4; ++r) acc[r] = bd;
        for (int kk = 0; kk < ID; ++kk) {
            const float wv = Wu2[kk * SD + d];
            #pragma unroll
            for (int r = 0; r < 4; ++r) acc[r] = fmaf(u[r0 + r][kk], wv, acc[r]);
        }
        #pragma unroll
        for (int r = 0; r < 4; ++r) xs[r0 + r][d] = up[r0 + r][d] + ftanh(acc[r]);
    }
    __syncthreads();
    const int w = t >> 6, lane = t & 63;
    #pragma unroll
    for (int rr = 0; rr < 2; ++rr) {
        const int r = w * 2 + rr;
        const float v0 = xs[r][lane], v1 = xs[r][lane + 64];
        float s = v0 + v1;
        #pragma unroll
        for (int m = 1; m < 64; m <<= 1) s += __shfl_xor(s, m, 64);
        const float mu = s * (1.0f / SD);
        const float d0 = v0 - mu, d1 = v1 - mu;
        float q = d0 * d0 + d1 * d1;
        #pragma unroll
        for (int m = 1; m < 64; m <<= 1) q += __shfl_xor(q, m, 64);
        const float inv = rsqrtf(q * (1.0f / SD) + 1e-5f);
        out[(size_t)(row0 + r) * SD + lane] = d0 * inv * lnw[lane] + lnb[lane];
        out[(size_t)(row0 + r) * SD + lane + 64] = d1 * inv * lnw[lane + 64] + lnb[lane + 64];
    }
}

extern "C" void kernel_launch(void* const* d_in, const int* in_sizes, int n_in,
                              void* d_out, int out_size, void* d_ws, size_t ws_size,
                              hipStream_t stream) {
    const float* h   = (const float*)d_in[0];
    const float* ef  = (const float*)d_in[1];
    const float* em  = (const float*)d_in[2];
    const float* Wm1 = (const float*)d_in[3];
    const float* bm1 = (const float*)d_in[4];
    const float* Wm2 = (const float*)d_in[5];
    const float* bm2 = (const float*)d_in[6];
    const float* Wg1 = (const float*)d_in[7];
    const float* bg1 = (const float*)d_in[8];
    const float* Wg2 = (const float*)d_in[9];
    const float* bg2 = (const float*)d_in[10];
    const float* Wu1 = (const float*)d_in[11];
    const float* bu1 = (const float*)d_in[12];
    const float* Wu2 = (const float*)d_in[13];
    const float* bu2 = (const float*)d_in[14];
    const float* lnw = (const float*)d_in[15];
    const float* lnb = (const float*)d_in[16];

    float* ws = (float*)d_ws;
    float* Hgi   = ws;
    float* Hgjt  = Hgi + (size_t)BN * ID;
    float* Hmi   = Hgjt + (size_t)BN * ID;
    float* Hmjt  = Hmi + (size_t)BN * ID;
    float* T     = Hmjt + (size_t)BN * ID;
    float* gsumv = T + (size_t)BN * ID;
    float* degv  = gsumv + BN;
    ushort* Bprep = (ushort*)(degv + BN);
    float* outp = (float*)d_out;

    k_prep_w<<<32, 64, 0, stream>>>(Wg1, Wm1, Bprep);
    k1_preproj<<<dim3(BN / 16, 4), 256, 0, stream>>>(h, Wg1, bg1, Wm1, bm1,
                                                     Hgi, Hgjt, Hmi, Hmjt);
    k2_edges<<<BN / NI, 256, 0, stream>>>(ef, em, Bprep, Hgi, Hmi, Hgjt, Hmjt,
                                          Wg2, bg2, T, gsumv, degv);
    k34_update<<<BN / 8, 256, 0, stream>>>(T, gsumv, degv, h, Wm2, bm2,
                                           Wu1, bu1, Wu2, bu2, lnw, lnb, outp);
}